// Round 11
// baseline (315.701 us; speedup 1.0000x reference)
//
#include <hip/hip_runtime.h>
#include <hip/hip_bf16.h>
#include <math.h>

#define N_NODES 50000
#define N_EDGES 800000
#define E_TOT   (N_EDGES + N_NODES)   // 850000 (with self-loops)
#define IN_CH 128
#define HID 32
#define HEADS 8
#define OUT_CH 64
#define NEG_SLOPE 0.2f
#define NBLK 196                      // ceil(50000/256)
#define M_BLK 64
#define GBLK 782                      // ceil(50000/64)
#define A2BLK 6250                    // 50000/8 nodes per block (2 nodes/wave)
#define LOG2E 1.4426950408889634f

__device__ __forceinline__ float lrelu(float x) { return x > 0.f ? x : NEG_SLOPE * x; }
// exp(lrelu(z)) = exp2(max(z*L, z*0.2L))  (branchless; valid since L>0)
__device__ __forceinline__ float explrelu(float z) {
    return exp2f(fmaxf(z * LOG2E, z * (NEG_SLOPE * LOG2E)));
}

__device__ __forceinline__ unsigned short f2bf(float f) {
    unsigned int u = __float_as_uint(f);
    unsigned int r = (u + 0x7FFFu + ((u >> 16) & 1u)) >> 16;   // round-nearest-even
    return (unsigned short)r;
}
__device__ __forceinline__ float bf2f(unsigned short u) {
    return __uint_as_float(((unsigned int)u) << 16);
}
__device__ __forceinline__ float bflo(unsigned int u) {       // low ushort -> float
    return __uint_as_float(u << 16);
}
__device__ __forceinline__ float bfhi(unsigned int u) {       // high ushort -> float
    return __uint_as_float(u & 0xFFFF0000u);
}

// ---------------- CSR build ----------------
__global__ void hist_kernel(const int* __restrict__ ei, int* __restrict__ deg) {
    int e = blockIdx.x * blockDim.x + threadIdx.x;
    if (e >= E_TOT) return;
    int d = (e < N_EDGES) ? ei[N_EDGES + e] : (e - N_EDGES);
    atomicAdd(&deg[d], 1);
}

__global__ void scan1_kernel(const int* __restrict__ deg, int* __restrict__ off,
                             int* __restrict__ bsum) {
    __shared__ int s[256];
    int b = blockIdx.x, t = threadIdx.x, g = b * 256 + t;
    int v = (g < N_NODES) ? deg[g] : 0;
    s[t] = v;
    __syncthreads();
    for (int d = 1; d < 256; d <<= 1) {
        int o = (t >= d) ? s[t - d] : 0;
        __syncthreads();
        s[t] += o;
        __syncthreads();
    }
    if (g < N_NODES) off[g] = s[t] - v;
    if (t == 255) bsum[b] = s[t];
}

__global__ void scan2_kernel(int* __restrict__ bsum, int nb) {
    __shared__ int s[256];
    int t = threadIdx.x;
    int v = (t < nb) ? bsum[t] : 0;
    s[t] = v;
    __syncthreads();
    for (int d = 1; d < 256; d <<= 1) {
        int o = (t >= d) ? s[t - d] : 0;
        __syncthreads();
        s[t] += o;
        __syncthreads();
    }
    if (t < nb) bsum[t] = s[t] - v;
}

__global__ void scan3_kernel(int* __restrict__ off, const int* __restrict__ bsum,
                             int* __restrict__ cur) {
    int b = blockIdx.x, t = threadIdx.x, g = b * 256 + t;
    if (g < N_NODES) {
        int v = off[g] + bsum[b];
        off[g] = v;
        cur[g] = v;
    }
    if (g == 0) off[N_NODES] = E_TOT;
}

__global__ void scatter_kernel(const int* __restrict__ ei, int* __restrict__ cur,
                               int* __restrict__ ssrc) {
    int e = blockIdx.x * blockDim.x + threadIdx.x;
    if (e >= E_TOT) return;
    int s, d;
    if (e < N_EDGES) { s = ei[e]; d = ei[N_EDGES + e]; }
    else             { s = d = e - N_EDGES; }
    int pos = atomicAdd(&cur[d], 1);
    ssrc[pos] = s;
}

// ---------------- GEMM1 (tiled, 64x256 tile) + alpha epilogue, bf16 h1 out ---
#define FMA4(accv, av, bv)                                                     \
    accv.x = fmaf(av, bv.x, accv.x); accv.y = fmaf(av, bv.y, accv.y);          \
    accv.z = fmaf(av, bv.z, accv.z); accv.w = fmaf(av, bv.w, accv.w);

__global__ __launch_bounds__(256) void gemm1_tiled(
    const float* __restrict__ x, const float* __restrict__ W1,
    const float* __restrict__ att_s, const float* __restrict__ att_d,
    unsigned short* __restrict__ h1b, float* __restrict__ as1, float* __restrict__ ad1) {
    __shared__ float As[M_BLK][IN_CH];   // 32 KB
    int t = threadIdx.x;
    int row0 = blockIdx.x * M_BLK;
#pragma unroll
    for (int i = 0; i < 8; ++i) {
        int f = t + i * 256;
        int r = f >> 5, c4 = (f & 31) * 4;
        int gr = row0 + r; if (gr >= N_NODES) gr = N_NODES - 1;
        *(float4*)&As[r][c4] = *(const float4*)&x[(size_t)gr * IN_CH + c4];
    }
    __syncthreads();
    int col0 = (t & 63) * 4;
    int rbase = (t >> 6) * 16;
    float4 acc[16];
#pragma unroll
    for (int m = 0; m < 16; ++m) acc[m] = make_float4(0.f, 0.f, 0.f, 0.f);

    for (int k = 0; k < IN_CH; k += 4) {
        float4 b0 = *(const float4*)&W1[(k + 0) * 256 + col0];
        float4 b1 = *(const float4*)&W1[(k + 1) * 256 + col0];
        float4 b2 = *(const float4*)&W1[(k + 2) * 256 + col0];
        float4 b3 = *(const float4*)&W1[(k + 3) * 256 + col0];
#pragma unroll
        for (int m = 0; m < 16; ++m) {
            float4 a = *(const float4*)&As[rbase + m][k];
            FMA4(acc[m], a.x, b0);
            FMA4(acc[m], a.y, b1);
            FMA4(acc[m], a.z, b2);
            FMA4(acc[m], a.w, b3);
        }
    }

    float4 s4 = *(const float4*)&att_s[col0];
    float4 d4 = *(const float4*)&att_d[col0];
    int head = col0 >> 5;
#pragma unroll
    for (int m = 0; m < 16; ++m) {
        int gr = row0 + rbase + m;
        if (gr < N_NODES) {
            ushort4 hb;
            hb.x = f2bf(acc[m].x); hb.y = f2bf(acc[m].y);
            hb.z = f2bf(acc[m].z); hb.w = f2bf(acc[m].w);
            *(ushort4*)&h1b[(size_t)gr * 256 + col0] = hb;
            float p = acc[m].x * s4.x + acc[m].y * s4.y + acc[m].z * s4.z + acc[m].w * s4.w;
            float q = acc[m].x * d4.x + acc[m].y * d4.y + acc[m].z * d4.z + acc[m].w * d4.w;
            p += __shfl_xor(p, 1); p += __shfl_xor(p, 2); p += __shfl_xor(p, 4);
            q += __shfl_xor(q, 1); q += __shfl_xor(q, 2); q += __shfl_xor(q, 4);
            if ((t & 7) == 0) {
                as1[gr * HEADS + head] = p;
                ad1[gr * HEADS + head] = q;
            }
        }
    }
}

// ---------------- Aggregate layer 1: 2 nodes/wave, 8-edge batched weights ---
__global__ __launch_bounds__(256) void agg1_kernel(
    const int* __restrict__ off, const int* __restrict__ ssrc,
    const unsigned short* __restrict__ h1b, const float* __restrict__ as1,
    const float* __restrict__ ad1, const float* __restrict__ b1,
    unsigned short* __restrict__ houtb) {
    int t = threadIdx.x;
    int lane = t & 63;
    int h = lane >> 3;
    int e8 = lane & 7;
    int c0 = lane * 4;
    int nA = blockIdx.x * 8 + (t >> 6) * 2;
    int nB = nA + 1;
    int iA = off[nA], endA = off[nA + 1];
    int iB = endA,    endB = off[nB + 1];       // CSR is contiguous
    float adwA = ad1[nA * HEADS + e8];
    float adwB = ad1[nB * HEADS + e8];
    float adhA = ad1[nA * HEADS + h];
    float adhB = ad1[nB * HEADS + h];
    float4 accA = make_float4(0.f, 0.f, 0.f, 0.f);
    float4 accB = make_float4(0.f, 0.f, 0.f, 0.f);
    float denA = 0.f, denB = 0.f;
    bool doA = iA + 8 <= endA, doB = iB + 8 <= endB;
    while (doA || doB) {
        // issue all loads up-front (clamped addresses always valid: deg >= 1)
        int svA = ssrc[min(iA + e8, endA - 1)];
        int svB = ssrc[min(iB + e8, endB - 1)];
        int seA = __shfl(svA, h);
        int seB = __shfl(svB, h);
        float zA = as1[seA * HEADS + e8] + adwA;
        float zB = as1[seB * HEADS + e8] + adwB;
        float wvA = explrelu(zA);
        float wvB = explrelu(zB);
        if (doA) {
#pragma unroll
            for (int j = 0; j < 8; ++j) {
                float wj = __shfl(wvA, j * 8 + h);
                int   sj = __shfl(svA, j);
                uint2 u = *(const uint2*)&h1b[(unsigned)sj * 256 + c0];
                denA += wj;
                accA.x = fmaf(wj, bflo(u.x), accA.x);
                accA.y = fmaf(wj, bfhi(u.x), accA.y);
                accA.z = fmaf(wj, bflo(u.y), accA.z);
                accA.w = fmaf(wj, bfhi(u.y), accA.w);
            }
            iA += 8;
        }
        if (doB) {
#pragma unroll
            for (int j = 0; j < 8; ++j) {
                float wj = __shfl(wvB, j * 8 + h);
                int   sj = __shfl(svB, j);
                uint2 u = *(const uint2*)&h1b[(unsigned)sj * 256 + c0];
                denB += wj;
                accB.x = fmaf(wj, bflo(u.x), accB.x);
                accB.y = fmaf(wj, bfhi(u.x), accB.y);
                accB.z = fmaf(wj, bflo(u.y), accB.z);
                accB.w = fmaf(wj, bfhi(u.y), accB.w);
            }
            iB += 8;
        }
        doA = iA + 8 <= endA;
        doB = iB + 8 <= endB;
    }
    for (; iA < endA; ++iA) {
        int s0 = ssrc[iA];
        float w0 = explrelu(as1[s0 * HEADS + h] + adhA);
        uint2 u = *(const uint2*)&h1b[(unsigned)s0 * 256 + c0];
        denA += w0;
        accA.x = fmaf(w0, bflo(u.x), accA.x);
        accA.y = fmaf(w0, bfhi(u.x), accA.y);
        accA.z = fmaf(w0, bflo(u.y), accA.z);
        accA.w = fmaf(w0, bfhi(u.y), accA.w);
    }
    for (; iB < endB; ++iB) {
        int s0 = ssrc[iB];
        float w0 = explrelu(as1[s0 * HEADS + h] + adhB);
        uint2 u = *(const uint2*)&h1b[(unsigned)s0 * 256 + c0];
        denB += w0;
        accB.x = fmaf(w0, bflo(u.x), accB.x);
        accB.y = fmaf(w0, bfhi(u.x), accB.y);
        accB.z = fmaf(w0, bflo(u.y), accB.z);
        accB.w = fmaf(w0, bfhi(u.y), accB.w);
    }
    float4 bv = *(const float4*)&b1[c0];
    {
        float r = __builtin_amdgcn_rcpf(denA);
        float vx = fmaf(accA.x, r, bv.x);
        float vy = fmaf(accA.y, r, bv.y);
        float vz = fmaf(accA.z, r, bv.z);
        float vw = fmaf(accA.w, r, bv.w);
        vx = vx > 0.f ? vx : expm1f(vx);
        vy = vy > 0.f ? vy : expm1f(vy);
        vz = vz > 0.f ? vz : expm1f(vz);
        vw = vw > 0.f ? vw : expm1f(vw);
        ushort4 ob;
        ob.x = f2bf(vx); ob.y = f2bf(vy); ob.z = f2bf(vz); ob.w = f2bf(vw);
        *(ushort4*)&houtb[(unsigned)nA * 256 + c0] = ob;
    }
    {
        float r = __builtin_amdgcn_rcpf(denB);
        float vx = fmaf(accB.x, r, bv.x);
        float vy = fmaf(accB.y, r, bv.y);
        float vz = fmaf(accB.z, r, bv.z);
        float vw = fmaf(accB.w, r, bv.w);
        vx = vx > 0.f ? vx : expm1f(vx);
        vy = vy > 0.f ? vy : expm1f(vy);
        vz = vz > 0.f ? vz : expm1f(vz);
        vw = vw > 0.f ? vw : expm1f(vw);
        ushort4 ob;
        ob.x = f2bf(vx); ob.y = f2bf(vy); ob.z = f2bf(vz); ob.w = f2bf(vw);
        *(ushort4*)&houtb[(unsigned)nB * 256 + c0] = ob;
    }
}

// ---------------- GEMM2 (tiled, 64x64 tile, bf16 in, 4x4 blocking) ----------
__global__ __launch_bounds__(256) void gemm2_tiled(
    const unsigned short* __restrict__ hinb, const float* __restrict__ W2,
    const float* __restrict__ att_s2, const float* __restrict__ att_d2,
    unsigned short* __restrict__ h2b, float* __restrict__ as2, float* __restrict__ ad2) {
    __shared__ float As[M_BLK][256];   // 64 KB
    int t = threadIdx.x;
    int row0 = blockIdx.x * M_BLK;
#pragma unroll
    for (int i = 0; i < 16; ++i) {
        int f = t + i * 256;
        int r = f >> 6, c4 = (f & 63) * 4;
        int gr = row0 + r; if (gr >= N_NODES) gr = N_NODES - 1;
        ushort4 u = *(const ushort4*)&hinb[(size_t)gr * 256 + c4];
        float4 v = make_float4(bf2f(u.x), bf2f(u.y), bf2f(u.z), bf2f(u.w));
        *(float4*)&As[r][c4] = v;
    }
    __syncthreads();
    int col0 = (t & 15) * 4;
    int rbase = (t >> 4) * 4;
    float4 acc[4];
#pragma unroll
    for (int m = 0; m < 4; ++m) acc[m] = make_float4(0.f, 0.f, 0.f, 0.f);

    for (int k = 0; k < 256; k += 4) {
        float4 b0 = *(const float4*)&W2[(k + 0) * 64 + col0];
        float4 b1 = *(const float4*)&W2[(k + 1) * 64 + col0];
        float4 b2 = *(const float4*)&W2[(k + 2) * 64 + col0];
        float4 b3 = *(const float4*)&W2[(k + 3) * 64 + col0];
#pragma unroll
        for (int m = 0; m < 4; ++m) {
            float4 a = *(const float4*)&As[rbase + m][k];
            FMA4(acc[m], a.x, b0);
            FMA4(acc[m], a.y, b1);
            FMA4(acc[m], a.z, b2);
            FMA4(acc[m], a.w, b3);
        }
    }

    float4 s4 = *(const float4*)&att_s2[col0];
    float4 d4 = *(const float4*)&att_d2[col0];
#pragma unroll
    for (int m = 0; m < 4; ++m) {
        int gr = row0 + rbase + m;
        if (gr < N_NODES) {
            ushort4 hb;
            hb.x = f2bf(acc[m].x); hb.y = f2bf(acc[m].y);
            hb.z = f2bf(acc[m].z); hb.w = f2bf(acc[m].w);
            *(ushort4*)&h2b[(size_t)gr * 64 + col0] = hb;
            float p = acc[m].x * s4.x + acc[m].y * s4.y + acc[m].z * s4.z + acc[m].w * s4.w;
            float q = acc[m].x * d4.x + acc[m].y * d4.y + acc[m].z * d4.z + acc[m].w * d4.w;
            p += __shfl_xor(p, 1); q += __shfl_xor(q, 1);
            p += __shfl_xor(p, 2); q += __shfl_xor(q, 2);
            p += __shfl_xor(p, 4); q += __shfl_xor(q, 4);
            p += __shfl_xor(p, 8); q += __shfl_xor(q, 8);
            if ((t & 15) == 0) { as2[gr] = p; ad2[gr] = q; }
        }
    }
}

// ---------------- Aggregate layer 2: 2 nodes/wave, 8-edge batched weights ---
__global__ __launch_bounds__(256) void agg2_kernel(
    const int* __restrict__ off, const int* __restrict__ ssrc,
    const unsigned short* __restrict__ h2b, const float* __restrict__ as2,
    const float* __restrict__ ad2, const float* __restrict__ b2,
    float* __restrict__ out) {
    int t = threadIdx.x;
    int lane = t & 63;
    int e8 = lane & 7;
    int nA = blockIdx.x * 8 + (t >> 6) * 2;
    int nB = nA + 1;
    int iA = off[nA], endA = off[nA + 1];
    int iB = endA,    endB = off[nB + 1];
    float advA = ad2[nA];
    float advB = ad2[nB];
    float accA = 0.f, denA = 0.f, accB = 0.f, denB = 0.f;
    bool doA = iA + 8 <= endA, doB = iB + 8 <= endB;
    while (doA || doB) {
        int svA = ssrc[min(iA + e8, endA - 1)];
        int svB = ssrc[min(iB + e8, endB - 1)];
        float wvA = explrelu(as2[svA] + advA);
        float wvB = explrelu(as2[svB] + advB);
        if (doA) {
#pragma unroll
            for (int j = 0; j < 8; ++j) {
                float wj = __shfl(wvA, j);
                int   sj = __shfl(svA, j);
                float v = bf2f(h2b[(unsigned)sj * 64 + lane]);
                denA += wj;
                accA = fmaf(wj, v, accA);
            }
            iA += 8;
        }
        if (doB) {
#pragma unroll
            for (int j = 0; j < 8; ++j) {
                float wj = __shfl(wvB, j);
                int   sj = __shfl(svB, j);
                float v = bf2f(h2b[(unsigned)sj * 64 + lane]);
                denB += wj;
                accB = fmaf(wj, v, accB);
            }
            iB += 8;
        }
        doA = iA + 8 <= endA;
        doB = iB + 8 <= endB;
    }
    for (; iA < endA; ++iA) {
        int s0 = ssrc[iA];
        float w0 = explrelu(as2[s0] + advA);
        denA += w0;
        accA = fmaf(w0, bf2f(h2b[(unsigned)s0 * 64 + lane]), accA);
    }
    for (; iB < endB; ++iB) {
        int s0 = ssrc[iB];
        float w0 = explrelu(as2[s0] + advB);
        denB += w0;
        accB = fmaf(w0, bf2f(h2b[(unsigned)s0 * 64 + lane]), accB);
    }
    float bb = b2[lane];
    out[(unsigned)nA * 64 + lane] = fmaf(accA, __builtin_amdgcn_rcpf(denA), bb);
    out[(unsigned)nB * 64 + lane] = fmaf(accB, __builtin_amdgcn_rcpf(denB), bb);
}

extern "C" void kernel_launch(void* const* d_in, const int* in_sizes, int n_in,
                              void* d_out, int out_size, void* d_ws, size_t ws_size,
                              hipStream_t stream) {
    const float* x    = (const float*)d_in[0];
    const int*   ei   = (const int*)d_in[1];
    const float* W1   = (const float*)d_in[2];
    const float* ats1 = (const float*)d_in[3];
    const float* atd1 = (const float*)d_in[4];
    const float* b1   = (const float*)d_in[5];
    const float* W2   = (const float*)d_in[6];
    const float* ats2 = (const float*)d_in[7];
    const float* atd2 = (const float*)d_in[8];
    const float* b2   = (const float*)d_in[9];
    float* out = (float*)d_out;

    char* ws = (char*)d_ws;
    size_t o = 0;
    auto alloc = [&](size_t bytes) { size_t r = o; o = (o + bytes + 255) & ~255UL; return r; };
    unsigned short* h1b   = (unsigned short*)(ws + alloc((size_t)N_NODES * 256 * 2));
    unsigned short* h2inb = (unsigned short*)(ws + alloc((size_t)N_NODES * 256 * 2));
    unsigned short* h2b   = (unsigned short*)(ws + alloc((size_t)N_NODES * 64 * 2));
    float* as1  = (float*)(ws + alloc((size_t)N_NODES * HEADS * 4));
    float* ad1  = (float*)(ws + alloc((size_t)N_NODES * HEADS * 4));
    float* as2  = (float*)(ws + alloc((size_t)N_NODES * 4));
    float* ad2  = (float*)(ws + alloc((size_t)N_NODES * 4));
    int*   deg  = (int*)(ws + alloc((size_t)N_NODES * 4));
    int*   off  = (int*)(ws + alloc((size_t)(N_NODES + 1) * 4));
    int*   cur  = (int*)(ws + alloc((size_t)N_NODES * 4));
    int*   bsum = (int*)(ws + alloc(256 * 4));
    int*   ssrc = (int*)(ws + alloc((size_t)E_TOT * 4));

    (void)hipMemsetAsync(deg, 0, (size_t)N_NODES * 4, stream);
    int eblk = (E_TOT + 255) / 256;
    hist_kernel<<<eblk, 256, 0, stream>>>(ei, deg);
    scan1_kernel<<<NBLK, 256, 0, stream>>>(deg, off, bsum);
    scan2_kernel<<<1, 256, 0, stream>>>(bsum, NBLK);
    scan3_kernel<<<NBLK, 256, 0, stream>>>(off, bsum, cur);
    scatter_kernel<<<eblk, 256, 0, stream>>>(ei, cur, ssrc);

    gemm1_tiled<<<GBLK, 256, 0, stream>>>(x, W1, ats1, atd1, h1b, as1, ad1);
    agg1_kernel<<<A2BLK, 256, 0, stream>>>(off, ssrc, h1b, as1, ad1, b1, h2inb);

    gemm2_tiled<<<GBLK, 256, 0, stream>>>(h2inb, W2, ats2, atd2, h2b, as2, ad2);
    agg2_kernel<<<A2BLK, 256, 0, stream>>>(off, ssrc, h2b, as2, ad2, b2, out);
}